// Round 11
// baseline (242.231 us; speedup 1.0000x reference)
//
#include <hip/hip_runtime.h>

#define M_DIM 16384
#define N_DIM 1024
#define K_DIM 4096

#define BM 256
#define BN 256
#define BK 64
#define NT (K_DIM / BK)

typedef __attribute__((ext_vector_type(4))) float f32x4;
typedef __attribute__((ext_vector_type(8))) short bf16x8;
typedef __attribute__((ext_vector_type(8))) unsigned short u16x8;

static __device__ __forceinline__ short f2bf(float f) {
  union { __bf16 h; short s; } u;
  u.h = (__bf16)f;
  return u.s;
}

static __device__ __forceinline__ void load_lds16(const void* g, void* l) {
  __builtin_amdgcn_global_load_lds(
      (const __attribute__((address_space(1))) void*)g,
      (__attribute__((address_space(3))) void*)l, 16, 0, 0);
}

// ---------- prepass: WbT[n][k] = bf16(sign(W[k][n])) ----------
__global__ __launch_bounds__(256) void wsign_transpose(
    const float* __restrict__ W, unsigned short* __restrict__ WbT) {
  __shared__ unsigned short tile[64][72];
  const int t  = (int)threadIdx.x;
  const int k0 = (int)(blockIdx.x >> 4) * 64;
  const int n0 = (int)(blockIdx.x & 15) * 64;
#pragma unroll
  for (int p = 0; p < 4; ++p) {
    const int r = p * 16 + (t >> 4);
    const int c = (t & 15) * 4;
    const float* src = W + (size_t)(k0 + r) * N_DIM + n0 + c;
#pragma unroll
    for (int j = 0; j < 4; ++j) {
      const float w = src[j];
      tile[r][c + j] = (w > 0.f) ? (unsigned short)0x3F80u
                                 : ((w < 0.f) ? (unsigned short)0xBF80u
                                              : (unsigned short)0u);
    }
  }
  __syncthreads();
  const int n  = t >> 2;
  const int kg = (t & 3) * 16;
  u16x8 o0, o1;
#pragma unroll
  for (int j = 0; j < 8; ++j) o0[j] = tile[kg + j][n];
#pragma unroll
  for (int j = 0; j < 8; ++j) o1[j] = tile[kg + 8 + j][n];
  unsigned short* dst = WbT + (size_t)(n0 + n) * K_DIM + k0 + kg;
  *(u16x8*)dst       = o0;
  *(u16x8*)(dst + 8) = o1;
}

// ---------- main GEMM: 256x256, BK=64, 8 waves, K-split-region 4-phase ----------
// A stored as 4 quarters [q][64 rows][64 k] (XOR-swizzled granules). Phases:
// ph1(mig0,k0) ph2(mig0,k1) ph3(mig1,k0) ph4(mig1,k1). Quarter q(wm*2+mig0) of
// cur frees at ph2 -> ph3 writes A(t+2)q02 there; q13 of nxt written at ph1.
// vmcnt(6)/(8)/(4) counted, never 0 in steady loop.
__global__ __launch_bounds__(512, 2) void gemm_ks(
    const float* __restrict__ X, const unsigned short* __restrict__ WbT,
    const float* __restrict__ bias, float* __restrict__ Z) {
  __shared__ __align__(16) unsigned short As[2][4 * 4096];  // 64 KiB
  __shared__ __align__(16) unsigned short Bs[2][BN * BK];   // 64 KiB

  const int t   = (int)threadIdx.x;
  const int l   = t & 63;
  const int wid = t >> 6;
  const int wm  = wid >> 2;  // 0..1
  const int wn  = wid & 3;   // 0..3

  const int bid = (int)blockIdx.x;
  const int swz = (bid & 7) * 32 + (bid >> 3);  // bijective: 256 = 8*32
  const int m0  = (swz >> 2) * BM;
  const int n0  = (swz & 3) * BN;

  // fragment read offsets (XOR-swizzled granules; measured 0 conflicts R1-R10)
  const int arow  = (l & 15) * 64;                      // within-quarter row
  const int bbase = (wn * 64 + (l & 15)) * BK;
  const int axk0  = (((l >> 4) + 0) ^ (l & 7)) << 3;
  const int axk1  = (((l >> 4) + 4) ^ (l & 7)) << 3;

  // A staging: thread -> (pair-row wr_row 0..127, granule-pair jj 0..3)
  const int wr_row = t >> 2, jj = t & 3;
  const int inner  = wr_row & 63;
  const int hi     = wr_row >> 6;                       // 0/1
  const int rowE   = hi ? (128 + inner) : inner;        // q0 / q2 rows
  const float* srcE = X + (size_t)(m0 + rowE) * K_DIM + jj * 16;
  const float* srcO = srcE + (size_t)64 * K_DIM;        // q1 / q3 rows
  const int dstE0 = (hi ? 2 : 0) * 4096 + inner * 64 + (((2 * jj) ^ (inner & 7)) << 3);
  const int dstE1 = (hi ? 2 : 0) * 4096 + inner * 64 + (((2 * jj + 1) ^ (inner & 7)) << 3);

  // B staging: linear LDS dest, inverse-swizzled global source
  const unsigned short* b_src[4];
  int b_dst[4];
#pragma unroll
  for (int i = 0; i < 4; ++i) {
    const int c = i * 512 + t;
    const int n = c >> 3, gp = c & 7;
    b_src[i] = WbT + (size_t)(n0 + n) * K_DIM + (gp ^ (n & 7)) * 8;
    b_dst[i] = c * 8;
  }

  f32x4 acc[8][4] = {};      // 128 acc regs
  f32x4 arE[4], arO[4];      // A staging reg sets (16+16)
  bf16x8 aR[4];              // per-phase A frags (16)
  bf16x8 bR0[4], bR1[4];     // B frags k0 / k1 (16+16)

#define SB0 __builtin_amdgcn_sched_barrier(0)
#define BAR do { SB0; __builtin_amdgcn_s_barrier(); SB0; } while (0)
#define WVM(N) do { asm volatile("s_waitcnt vmcnt(" #N ")" ::: "memory"); SB0; } while (0)
#define WLG0 do { asm volatile("s_waitcnt lgkmcnt(0)" ::: "memory"); SB0; } while (0)

#define LD_ARE(KT)                                                         \
  do { SB0;                                                                \
    arE[0] = *(const f32x4*)(srcE + (KT));                                 \
    arE[1] = *(const f32x4*)(srcE + (KT) + 4);                             \
    arE[2] = *(const f32x4*)(srcE + (KT) + 8);                             \
    arE[3] = *(const f32x4*)(srcE + (KT) + 12); SB0;                       \
  } while (0)
#define LD_ARO(KT)                                                         \
  do { SB0;                                                                \
    arO[0] = *(const f32x4*)(srcO + (KT));                                 \
    arO[1] = *(const f32x4*)(srcO + (KT) + 4);                             \
    arO[2] = *(const f32x4*)(srcO + (KT) + 8);                             \
    arO[3] = *(const f32x4*)(srcO + (KT) + 12); SB0;                       \
  } while (0)
#define WR_AR(AR, BUF, QOFS)                                               \
  do {                                                                     \
    u16x8 v0, v1;                                                          \
    _Pragma("unroll") for (int q = 0; q < 4; ++q) {                        \
      v0[q]     = (unsigned short)f2bf(AR[0][q]);                          \
      v0[4 + q] = (unsigned short)f2bf(AR[1][q]);                          \
      v1[q]     = (unsigned short)f2bf(AR[2][q]);                          \
      v1[4 + q] = (unsigned short)f2bf(AR[3][q]);                          \
    }                                                                      \
    *(u16x8*)(&As[BUF][dstE0 + (QOFS)]) = v0;                              \
    *(u16x8*)(&As[BUF][dstE1 + (QOFS)]) = v1;                              \
  } while (0)
#define DMA_B2(KT, BUF, I0)                                                \
  do { SB0;                                                                \
    _Pragma("unroll") for (int i = (I0); i < (I0) + 2; ++i)                \
      load_lds16(b_src[i] + (KT), &Bs[BUF][b_dst[i]]);                     \
    SB0;                                                                   \
  } while (0)
#define RD_A(MIG, KK, AB)                                                  \
  do { SB0;                                                                \
    _Pragma("unroll") for (int mi = 0; mi < 4; ++mi)                       \
      aR[mi] = *(const bf16x8*)((AB) + (wm * 2 + (MIG)) * 4096 + arow +    \
                                mi * 1024 + ((KK) ? axk1 : axk0));         \
    SB0;                                                                   \
  } while (0)
#define RD_B(SET, KK, BB)                                                  \
  do { SB0;                                                                \
    _Pragma("unroll") for (int nj = 0; nj < 4; ++nj)                       \
      SET[nj] = *(const bf16x8*)((BB) + bbase + nj * 1024 +                \
                                 ((KK) ? axk1 : axk0));                    \
    SB0;                                                                   \
  } while (0)
#define MFMA16(MIG, BSET)                                                  \
  do { __builtin_amdgcn_s_setprio(1);                                      \
    _Pragma("unroll") for (int mi = 0; mi < 4; ++mi)                       \
      _Pragma("unroll") for (int nj = 0; nj < 4; ++nj)                     \
        acc[(MIG)*4 + mi][nj] = __builtin_amdgcn_mfma_f32_16x16x32_bf16(   \
            aR[mi], BSET[nj], acc[(MIG)*4 + mi][nj], 0, 0, 0);             \
    __builtin_amdgcn_s_setprio(0);                                         \
  } while (0)

  // ---- prologue: tile0 complete in buf0; A(1)q02 in buf1; arO<-A(1)q13 ----
  LD_ARE(0); LD_ARO(0);
  WVM(0);
  WR_AR(arE, 0, 0); WR_AR(arO, 0, 4096);
  DMA_B2(0, 0, 0); DMA_B2(0, 0, 2);   // B(0): 4 vm
  LD_ARE(BK);                          // A(1)q02: 4 vm
  WVM(0);
  WR_AR(arE, 1, 0);                    // buf1 q02
  LD_ARO(BK);                          // A(1)q13 in flight: Q=[4]
  WLG0;
  BAR;

  // ---- steady: t = 0 .. NT-3 ----
  for (int tt = 0; tt <= NT - 3; ++tt) {
    const int cur = tt & 1, nxt = cur ^ 1;
    const unsigned short* Ab = As[cur];
    const unsigned short* Bb = Bs[cur];
    const int kt1 = (tt + 1) * BK, kt2 = (tt + 2) * BK;
    // ph1 (mig0,k0): Q[4] +6 -> vmcnt(6) retires Aq13(t+1); write q13->nxt
    RD_A(0, 0, Ab);
    RD_B(bR0, 0, Bb);
    LD_ARE(kt2);                  // A(t+2)q02 regs
    DMA_B2(kt1, nxt, 0);          // B(t+1) part1
    WVM(6);
    WR_AR(arO, nxt, 4096);        // A(t+1) q1,q3
    BAR; WLG0;
    MFMA16(0, bR0);
    BAR;
    // ph2 (mig0,k1)
    RD_A(0, 1, Ab);
    RD_B(bR1, 1, Bb);
    LD_ARO(kt2);                  // A(t+2)q13 regs
    DMA_B2(kt1, nxt, 2);          // B(t+1) part2
    BAR; WLG0;
    MFMA16(0, bR1);
    BAR;
    // ph3 (mig1,k0): q02 of cur freed at ph2 -> write A(t+2)q02 there
    RD_A(1, 0, Ab);
    WVM(8);                       // retire A(t+2)q02 regs
    WR_AR(arE, cur, 0);
    BAR; WLG0;
    MFMA16(1, bR0);
    BAR;
    // ph4 (mig1,k1): retire B(t+1) before publishing barrier
    RD_A(1, 1, Ab);
    WVM(4);
    BAR; WLG0;
    MFMA16(1, bR1);
    BAR;
  }

  // ---- tile NT-2: stage only B(NT-1); write A(NT-1)q13 ----
  {
    const int cur = (NT - 2) & 1, nxt = cur ^ 1;
    const unsigned short* Ab = As[cur];
    const unsigned short* Bb = Bs[cur];
    const int kt1 = (NT - 1) * BK;
    RD_A(0, 0, Ab);
    RD_B(bR0, 0, Bb);
    DMA_B2(kt1, nxt, 0);          // Q = [Aq13(NT-1):4, Bp1:2]
    WVM(2);
    WR_AR(arO, nxt, 4096);
    BAR; WLG0;
    MFMA16(0, bR0);
    BAR;
    RD_A(0, 1, Ab);
    RD_B(bR1, 1, Bb);
    DMA_B2(kt1, nxt, 2);
    BAR; WLG0;
    MFMA16(0, bR1);
    BAR;
    RD_A(1, 0, Ab);
    BAR; WLG0;
    MFMA16(1, bR0);
    BAR;
    RD_A(1, 1, Ab);
    WVM(0);                       // retire B(NT-1)
    BAR; WLG0;
    MFMA16(1, bR1);
    BAR;
  }
  // ---- tile NT-1: pure compute ----
  {
    const unsigned short* Ab = As[(NT - 1) & 1];
    const unsigned short* Bb = Bs[(NT - 1) & 1];
    RD_A(0, 0, Ab);
    RD_B(bR0, 0, Bb);
    WLG0;
    MFMA16(0, bR0);
    RD_A(0, 1, Ab);
    RD_B(bR1, 1, Bb);
    WLG0;
    MFMA16(0, bR1);
    RD_A(1, 0, Ab);
    WLG0;
    MFMA16(1, bR0);
    RD_A(1, 1, Ab);
    WLG0;
    MFMA16(1, bR1);
  }

  // ---- epilogue: + sign(bias); D frag: col = l&15, row = (l>>4)*4 + j ----
#pragma unroll
  for (int ni = 0; ni < 4; ++ni) {
    const int col = n0 + wn * 64 + ni * 16 + (l & 15);
    const float b  = bias[col];
    const float bs = (b > 0.f) ? 1.f : ((b < 0.f) ? -1.f : 0.f);
#pragma unroll
    for (int mi = 0; mi < 8; ++mi) {
      const int row = m0 + wm * 128 + mi * 16 + ((l >> 4) << 2);
#pragma unroll
      for (int j = 0; j < 4; ++j)
        Z[(size_t)(row + j) * N_DIM + col] = acc[mi][ni][j] + bs;
    }
  }
#undef SB0
#undef BAR
#undef WVM
#undef WLG0
#undef LD_ARE
#undef LD_ARO
#undef WR_AR
#undef DMA_B2
#undef RD_A
#undef RD_B
#undef MFMA16
}

// ---------- slow-but-correct fallback ----------
__global__ __launch_bounds__(256) void naive_fb(
    const float* __restrict__ X, const float* __restrict__ W,
    const float* __restrict__ bias, float* __restrict__ Z) {
  const size_t id = (size_t)blockIdx.x * 256 + threadIdx.x;
  const int m = (int)(id >> 10), n = (int)(id & 1023);
  float acc = 0.f;
  for (int k = 0; k < K_DIM; ++k) {
    const float w = W[(size_t)k * N_DIM + n];
    const float s = (w > 0.f) ? 1.f : ((w < 0.f) ? -1.f : 0.f);
    acc += X[(size_t)m * K_DIM + k] * s;
  }
  const float b = bias[n];
  Z[id] = acc + ((b > 0.f) ? 1.f : ((b < 0.f) ? -1.f : 0.f));
}

extern "C" void kernel_launch(void* const* d_in, const int* in_sizes, int n_in,
                              void* d_out, int out_size, void* d_ws, size_t ws_size,
                              hipStream_t stream) {
  const float* X    = (const float*)d_in[0];
  const float* W    = (const float*)d_in[1];
  const float* bias = (const float*)d_in[2];
  float* Z = (float*)d_out;

  const size_t needW = (size_t)N_DIM * K_DIM * sizeof(unsigned short);  // 8 MiB
  if (ws_size >= needW) {
    unsigned short* WbT = (unsigned short*)d_ws;
    wsign_transpose<<<dim3((K_DIM / 64) * (N_DIM / 64)), dim3(256), 0, stream>>>(W, WbT);
    gemm_ks<<<dim3((M_DIM / BM) * (N_DIM / BN)), dim3(512), 0, stream>>>(X, WbT, bias, Z);
  } else {
    naive_fb<<<dim3((size_t)M_DIM * N_DIM / 256), dim3(256), 0, stream>>>(X, W, bias, Z);
  }
}

// Round 12
// 189.019 us; speedup vs baseline: 1.2815x; 1.2815x over previous
//
#include <hip/hip_runtime.h>

#define M_DIM 16384
#define N_DIM 1024
#define K_DIM 4096

#define BM 256
#define BN 256
#define BK 64
#define NT (K_DIM / BK)

typedef __attribute__((ext_vector_type(4))) float f32x4;
typedef __attribute__((ext_vector_type(8))) short bf16x8;
typedef __attribute__((ext_vector_type(8))) unsigned short u16x8;

static __device__ __forceinline__ short f2bf(float f) {
  union { __bf16 h; short s; } u;
  u.h = (__bf16)f;   // RNE; pairs pack into v_cvt_pk_bf16_f32
  return u.s;
}

static __device__ __forceinline__ void load_lds16(const void* g, void* l) {
  __builtin_amdgcn_global_load_lds(
      (const __attribute__((address_space(1))) void*)g,
      (__attribute__((address_space(3))) void*)l, 16, 0, 0);
}

// ---------- prepass: WbT[n][k] = bf16(sign(W[k][n])) ----------
__global__ __launch_bounds__(256) void wsign_transpose(
    const float* __restrict__ W, unsigned short* __restrict__ WbT) {
  __shared__ unsigned short tile[64][72];
  const int t  = (int)threadIdx.x;
  const int k0 = (int)(blockIdx.x >> 4) * 64;
  const int n0 = (int)(blockIdx.x & 15) * 64;
#pragma unroll
  for (int p = 0; p < 4; ++p) {
    const int r = p * 16 + (t >> 4);
    const int c = (t & 15) * 4;
    const float* src = W + (size_t)(k0 + r) * N_DIM + n0 + c;
#pragma unroll
    for (int j = 0; j < 4; ++j) {
      const float w = src[j];
      tile[r][c + j] = (w > 0.f) ? (unsigned short)0x3F80u
                                 : ((w < 0.f) ? (unsigned short)0xBF80u
                                              : (unsigned short)0u);
    }
  }
  __syncthreads();
  const int n  = t >> 2;
  const int kg = (t & 3) * 16;
  u16x8 o0, o1;
#pragma unroll
  for (int j = 0; j < 8; ++j) o0[j] = tile[kg + j][n];
#pragma unroll
  for (int j = 0; j < 8; ++j) o1[j] = tile[kg + 8 + j][n];
  unsigned short* dst = WbT + (size_t)(n0 + n) * K_DIM + k0 + kg;
  *(u16x8*)dst       = o0;
  *(u16x8*)(dst + 8) = o1;
}

// ---------- main GEMM: R9's counted-lgkm pipeline, mask-fenced ----------
// sched_barrier(0xF): ALU/VALU/SALU/MFMA may cross (compiler interleaves
// cvt + MFMA freely); VMEM and DS may NOT (preserves the counted-wait FIFO
// ledger). Full sched_barrier(0) only after pre-MFMA lgkm waits (rule #18)
// and around the two barriers per tile.
__global__ __launch_bounds__(512, 2) void gemm_r9f(
    const float* __restrict__ X, const unsigned short* __restrict__ WbT,
    const float* __restrict__ bias, float* __restrict__ Z) {
  __shared__ __align__(16) unsigned short As[2][BM * BK];  // 64 KiB
  __shared__ __align__(16) unsigned short Bs[2][BN * BK];  // 64 KiB

  const int t   = (int)threadIdx.x;
  const int l   = t & 63;
  const int wid = t >> 6;
  const int wm  = wid >> 2;  // 0..1
  const int wn  = wid & 3;   // 0..3

  const int bid = (int)blockIdx.x;
  const int swz = (bid & 7) * 32 + (bid >> 3);  // bijective: 256 = 8*32
  const int m0  = (swz >> 2) * BM;
  const int n0  = (swz & 3) * BN;

  const int abase = (wm * 128 + (l & 15)) * BK;
  const int bbase = (wn * 64 + (l & 15)) * BK;
  const int axk0  = (((l >> 4) + 0) ^ (l & 7)) << 3;
  const int axk1  = (((l >> 4) + 4) ^ (l & 7)) << 3;

  // A staging: thread owns rows {i*64 + t>>3}, k-granule t&7
  const float* sA0 = X + (size_t)(m0 +   0 + (t >> 3)) * K_DIM + (t & 7) * 8;
  const float* sA1 = X + (size_t)(m0 +  64 + (t >> 3)) * K_DIM + (t & 7) * 8;
  const float* sA2 = X + (size_t)(m0 + 128 + (t >> 3)) * K_DIM + (t & 7) * 8;
  const float* sA3 = X + (size_t)(m0 + 192 + (t >> 3)) * K_DIM + (t & 7) * 8;
  const int adst = (t >> 3) * BK + (((t & 7) ^ ((t >> 3) & 7)) << 3);

  // B staging: linear LDS dest, inverse-swizzled global source
  const unsigned short* b_src[4];
  int b_dst[4];
#pragma unroll
  for (int i = 0; i < 4; ++i) {
    const int c = i * 512 + t;
    const int n = c >> 3, gp = c & 7;
    b_src[i] = WbT + (size_t)(n0 + n) * K_DIM + (gp ^ (n & 7)) * 8;
    b_dst[i] = c * 8;
  }

  f32x4 acc[8][4] = {};      // 128 acc regs
  f32x4 ar[4][2];            // A(t+1) staging (32)
  bf16x8 a0F[4], a1F[4];     // ping/pong A frags (16+16)
  bf16x8 b0F[4], b1F[4];     // kk0 / kk1 B frags (16+16)

#define SB0 __builtin_amdgcn_sched_barrier(0)
#define SBF __builtin_amdgcn_sched_barrier(0xF)  // block VMEM+DS, allow rest
#define BAR do { SB0; __builtin_amdgcn_s_barrier(); SB0; } while (0)
#define WVM(N) do { asm volatile("s_waitcnt vmcnt(" #N ")" ::: "memory"); SBF; } while (0)
#define WLG(N) do { asm volatile("s_waitcnt lgkmcnt(" #N ")" ::: "memory"); SB0; } while (0)

#define LD_A8(KT)                                                          \
  do { SBF;                                                                \
    ar[0][0] = *(const f32x4*)(sA0 + (KT));                                \
    ar[0][1] = *(const f32x4*)(sA0 + (KT) + 4);                            \
    ar[1][0] = *(const f32x4*)(sA1 + (KT));                                \
    ar[1][1] = *(const f32x4*)(sA1 + (KT) + 4);                            \
    ar[2][0] = *(const f32x4*)(sA2 + (KT));                                \
    ar[2][1] = *(const f32x4*)(sA2 + (KT) + 4);                            \
    ar[3][0] = *(const f32x4*)(sA3 + (KT));                                \
    ar[3][1] = *(const f32x4*)(sA3 + (KT) + 4); SBF;                       \
  } while (0)
#define WR_AH(BUF, H)                                                      \
  do { SBF;                                                                \
    _Pragma("unroll") for (int j = 2 * (H); j < 2 * (H) + 2; ++j) {        \
      u16x8 v;                                                             \
      _Pragma("unroll") for (int q = 0; q < 4; ++q) {                      \
        v[q]     = (unsigned short)f2bf(ar[j][0][q]);                      \
        v[4 + q] = (unsigned short)f2bf(ar[j][1][q]);                      \
      }                                                                    \
      *(u16x8*)(&As[BUF][adst + j * 4096]) = v;                            \
    } SBF;                                                                 \
  } while (0)
#define DMA_B4(KT, BUF)                                                    \
  do { SBF;                                                                \
    _Pragma("unroll") for (int i = 0; i < 4; ++i)                          \
      load_lds16(b_src[i] + (KT), &Bs[BUF][b_dst[i]]);                     \
    SBF;                                                                   \
  } while (0)
#define RD_A(DST, KK, MIG, AB)                                             \
  do { SBF;                                                                \
    _Pragma("unroll") for (int mi = 0; mi < 4; ++mi)                       \
      DST[mi] = *(const bf16x8*)((AB) + abase + ((MIG)*4 + mi) * 1024 +    \
                                 ((KK) ? axk1 : axk0));                    \
    SBF;                                                                   \
  } while (0)
#define RD_B(DST, KK, BB)                                                  \
  do { SBF;                                                                \
    _Pragma("unroll") for (int nj = 0; nj < 4; ++nj)                       \
      DST[nj] = *(const bf16x8*)((BB) + bbase + nj * 1024 +                \
                                 ((KK) ? axk1 : axk0));                    \
    SBF;                                                                   \
  } while (0)
#define MFMA16(MIG, AF, BF)                                                \
  do { __builtin_amdgcn_s_setprio(1);                                      \
    _Pragma("unroll") for (int mi = 0; mi < 4; ++mi)                       \
      _Pragma("unroll") for (int nj = 0; nj < 4; ++nj)                     \
        acc[(MIG)*4 + mi][nj] = __builtin_amdgcn_mfma_f32_16x16x32_bf16(   \
            AF[mi], BF[nj], acc[(MIG)*4 + mi][nj], 0, 0, 0);               \
    __builtin_amdgcn_s_setprio(0);                                         \
  } while (0)

  // ---- prologue ----
  LD_A8(0);                      // A(0) x8 vm
  WVM(0);
  WR_AH(0, 0); WR_AH(0, 1);      // A(0) -> buf0 (4w)
  DMA_B4(0, 0);                  // B(0) x4 vm
  LD_A8(BK);                     // A(1) x8 vm -> [B(0):4, A(1):8]
  WVM(8);                        // retire B(0)
  WLG(0);                        // drain A(0) writes
  BAR;                           // publish buf0
  RD_A(a0F, 0, 0, As[0]);        // lgkm [a0:4]
  RD_B(b0F, 0, Bs[0]);           // lgkm [a0:4, b0:4]
  // invariant: lgkm [a0:4, b0:4]; vm [A(t+1):8]

  // ---- steady: tt = 0 .. NT-3 ----
  for (int tt = 0; tt <= NT - 3; ++tt) {
    const int cur = tt & 1, nxt = cur ^ 1;
    const unsigned short* Ab = As[cur];
    const unsigned short* Bb = Bs[cur];
    // PH1 (kk0,m0): issue a1 <- (kk0,m1); B(t+1) DMA
    RD_A(a1F, 0, 1, Ab);         // lgkm [a0:4, b0:4, a1:4]
    DMA_B4((tt + 1) * BK, nxt);  // vm [A(t+1):8, B(t+1):4]
    WLG(4);                      // retire a0,b0
    MFMA16(0, a0F, b0F);
    // PH2 (kk0,m1): issue a0 <- (kk1,m0), b1 <- kk1; A(t+1) regs -> h1
    RD_A(a0F, 1, 0, Ab);
    RD_B(b1F, 1, Bb);            // lgkm [a1:4, a0:4, b1:4]
    WVM(4);                      // retire A(t+1) x8
    WR_AH(nxt, 0);               // lgkm [a1, a0, b1, w2]
    WLG(10);                     // retire a1
    MFMA16(1, a1F, b0F);
    // PH3 (kk1,m0): write h2; issue a1 <- (kk1,m1); issue A(t+2); publish
    WR_AH(nxt, 1);               // lgkm [a0, b1, w2, w2]
    RD_A(a1F, 1, 1, Ab);         // lgkm [a0, b1, w2, w2, a1]
    LD_A8((tt + 2) * BK);        // vm [B(t+1):4, A(t+2):8]
    WVM(8);                      // retire B(t+1) (publish requirement)
    WLG(4);                      // retire a0,b1,all writes; a1 stays
    MFMA16(0, a0F, b1F);
    BAR;                         // publish nxt
    // PH4 (kk1,m1): issue next tile's a0,b0 from nxt
    RD_A(a0F, 0, 0, As[nxt]);
    RD_B(b0F, 0, Bs[nxt]);       // lgkm [a1:4, a0:4, b0:4]
    WLG(8);                      // retire a1
    MFMA16(1, a1F, b1F);
    BAR;                         // anti-overwrite for cur
  }

  // ---- tile NT-2: steady minus LD_A8 ----
  {
    const int cur = (NT - 2) & 1, nxt = cur ^ 1;
    const unsigned short* Ab = As[cur];
    const unsigned short* Bb = Bs[cur];
    RD_A(a1F, 0, 1, Ab);
    DMA_B4((NT - 1) * BK, nxt);
    WLG(4);
    MFMA16(0, a0F, b0F);
    RD_A(a0F, 1, 0, Ab);
    RD_B(b1F, 1, Bb);
    WVM(4);                      // retire A(NT-1) x8
    WR_AH(nxt, 0);
    WLG(10);
    MFMA16(1, a1F, b0F);
    WR_AH(nxt, 1);
    RD_A(a1F, 1, 1, Ab);
    WVM(0);                      // retire B(NT-1) (nothing else in flight)
    WLG(4);
    MFMA16(0, a0F, b1F);
    BAR;                         // publish
    RD_A(a0F, 0, 0, As[nxt]);
    RD_B(b0F, 0, Bs[nxt]);
    WLG(8);
    MFMA16(1, a1F, b1F);
    BAR;
  }
  // ---- tile NT-1: pure compute ----
  {
    const unsigned short* Ab = As[(NT - 1) & 1];
    const unsigned short* Bb = Bs[(NT - 1) & 1];
    RD_A(a1F, 0, 1, Ab);
    WLG(4);
    MFMA16(0, a0F, b0F);
    RD_A(a0F, 1, 0, Ab);
    RD_B(b1F, 1, Bb);
    WLG(8);
    MFMA16(1, a1F, b0F);
    RD_A(a1F, 1, 1, Ab);
    WLG(4);
    MFMA16(0, a0F, b1F);
    WLG(0);
    MFMA16(1, a1F, b1F);
  }

  // ---- epilogue: + sign(bias); D frag: col = l&15, row = (l>>4)*4 + j ----
#pragma unroll
  for (int ni = 0; ni < 4; ++ni) {
    const int col = n0 + wn * 64 + ni * 16 + (l & 15);
    const float b  = bias[col];
    const float bs = (b > 0.f) ? 1.f : ((b < 0.f) ? -1.f : 0.f);
#pragma unroll
    for (int mi = 0; mi < 8; ++mi) {
      const int row = m0 + wm * 128 + mi * 16 + ((l >> 4) << 2);
#pragma unroll
      for (int j = 0; j < 4; ++j)
        Z[(size_t)(row + j) * N_DIM + col] = acc[mi][ni][j] + bs;
    }
  }
#undef SB0
#undef SBF
#undef BAR
#undef WVM
#undef WLG
#undef LD_A8
#undef WR_AH
#undef DMA_B4
#undef RD_A
#undef RD_B
#undef MFMA16
}

// ---------- slow-but-correct fallback ----------
__global__ __launch_bounds__(256) void naive_fb(
    const float* __restrict__ X, const float* __restrict__ W,
    const float* __restrict__ bias, float* __restrict__ Z) {
  const size_t id = (size_t)blockIdx.x * 256 + threadIdx.x;
  const int m = (int)(id >> 10), n = (int)(id & 1023);
  float acc = 0.f;
  for (int k = 0; k < K_DIM; ++k) {
    const float w = W[(size_t)k * N_DIM + n];
    const float s = (w > 0.f) ? 1.f : ((w < 0.f) ? -1.f : 0.f);
    acc += X[(size_t)m * K_DIM + k] * s;
  }
  const float b = bias[n];
  Z[id] = acc + ((b > 0.f) ? 1.f : ((b < 0.f) ? -1.f : 0.f));
}

extern "C" void kernel_launch(void* const* d_in, const int* in_sizes, int n_in,
                              void* d_out, int out_size, void* d_ws, size_t ws_size,
                              hipStream_t stream) {
  const float* X    = (const float*)d_in[0];
  const float* W    = (const float*)d_in[1];
  const float* bias = (const float*)d_in[2];
  float* Z = (float*)d_out;

  const size_t needW = (size_t)N_DIM * K_DIM * sizeof(unsigned short);  // 8 MiB
  if (ws_size >= needW) {
    unsigned short* WbT = (unsigned short*)d_ws;
    wsign_transpose<<<dim3((K_DIM / 64) * (N_DIM / 64)), dim3(256), 0, stream>>>(W, WbT);
    gemm_r9f<<<dim3((M_DIM / BM) * (N_DIM / BN)), dim3(512), 0, stream>>>(X, WbT, bias, Z);
  } else {
    naive_fb<<<dim3((size_t)M_DIM * N_DIM / 256), dim3(256), 0, stream>>>(X, W, bias, Z);
  }
}